// Round 1
// 2378.376 us; speedup vs baseline: 1.0059x; 1.0059x over previous
//
#include <hip/hip_runtime.h>
#include <hip/hip_bf16.h>

#define S_LEN 2048
#define D_DIM 64
#define TQ    16
#define SROW  2056   // 2048 + 8 pad: rows stay 16B-aligned, banks rotate +4/row

typedef __bf16 bf16x8 __attribute__((ext_vector_type(8)));
typedef __bf16 bf16x4 __attribute__((ext_vector_type(4)));
typedef float  f32x4  __attribute__((ext_vector_type(4)));

__global__ __launch_bounds__(256, 2)
void sdpa_kernel(const float* __restrict__ Q, const float* __restrict__ K,
                 const float* __restrict__ V, const int* __restrict__ mask,
                 const int* __restrict__ scale_p,
                 float* __restrict__ out, float* __restrict__ att)
{
    __shared__ __bf16 Ss[TQ][SROW];
    __shared__ float  Mw[4][TQ];   // per-wave row max
    __shared__ float  Lw[4][TQ];   // per-wave row sum (relative to Mw)

    const int tid  = threadIdx.x;
    const int lane = tid & 63;
    const int wv   = tid >> 6;      // wave 0..3
    const int lm   = lane & 15;     // MFMA n / m index
    const int lq   = lane >> 4;     // MFMA quad 0..3

    const int qt = blockIdx.x;      // q tile 0..127
    const int bh = blockIdx.y;      // 0..63
    const int q0 = qt * TQ;

    const float rscale = 1.0f / (float)(*scale_p);

    // ---------- Q fragments (A operand), scale folded in ----------
    bf16x8 qf[2];
    {
        const float* qp = Q + ((size_t)bh * S_LEN + q0 + lm) * D_DIM + lq * 8;
        #pragma unroll
        for (int c = 0; c < 2; ++c) {
            float4 a = *(const float4*)(qp + c * 32);
            float4 b = *(const float4*)(qp + c * 32 + 4);
            qf[c][0] = (__bf16)(a.x * rscale); qf[c][1] = (__bf16)(a.y * rscale);
            qf[c][2] = (__bf16)(a.z * rscale); qf[c][3] = (__bf16)(a.w * rscale);
            qf[c][4] = (__bf16)(b.x * rscale); qf[c][5] = (__bf16)(b.y * rscale);
            qf[c][6] = (__bf16)(b.z * rscale); qf[c][7] = (__bf16)(b.w * rscale);
        }
    }

    // ---------- Phase A: S = (Q/scale) K^T -> LDS bf16, fused mask + online (m,l) ----------
    // Lane (lq,lm) produces rows lq*4+i, col kt+lm. Online stats kept per row in registers,
    // computed from the bf16-ROUNDED stored value so all-masked rows stay exact (p = 1/2048).
    float mrow[4], lrow[4];
    #pragma unroll
    for (int i = 0; i < 4; ++i) { mrow[i] = -3.0e38f; lrow[i] = 0.f; }

    {
        const float* kb = K + (size_t)bh * S_LEN * D_DIM;
        const int key0 = wv * (S_LEN / 4);          // 512 keys per wave
        const int* mp = mask + ((size_t)bh * S_LEN + q0 + lq * 4) * S_LEN + lm;
        for (int t = 0; t < 32; ++t) {
            const int kt = key0 + t * 16;
            const float* kp = kb + (size_t)(kt + lm) * D_DIM + lq * 8;
            f32x4 acc = {0.f, 0.f, 0.f, 0.f};
            #pragma unroll
            for (int c = 0; c < 2; ++c) {
                float4 a = *(const float4*)(kp + c * 32);
                float4 b = *(const float4*)(kp + c * 32 + 4);
                bf16x8 kf;
                kf[0] = (__bf16)a.x; kf[1] = (__bf16)a.y;
                kf[2] = (__bf16)a.z; kf[3] = (__bf16)a.w;
                kf[4] = (__bf16)b.x; kf[5] = (__bf16)b.y;
                kf[6] = (__bf16)b.z; kf[7] = (__bf16)b.w;
                acc = __builtin_amdgcn_mfma_f32_16x16x32_bf16(qf[c], kf, acc, 0, 0, 0);
            }
            const int col = kt + lm;
            #pragma unroll
            for (int i = 0; i < 4; ++i) {
                const int mv = mp[(size_t)i * S_LEN + kt];          // mask[q0+lq*4+i][col]
                const __bf16 sb = (mv == 0) ? (__bf16)(-1.0e9f) : (__bf16)acc[i];
                Ss[lq * 4 + i][col] = sb;                           // row=lq*4+i, col
                const float sf = (float)sb;                         // rounded value (matches store)
                // branch-free 1-exp online update of (m,l)
                const float d = sf - mrow[i];
                const float e = __expf(-fabsf(d));
                lrow[i] = (d <= 0.f) ? (lrow[i] + e) : fmaf(lrow[i], e, 1.0f);
                mrow[i] = fmaxf(mrow[i], sf);
            }
        }
        // combine across the 16 lanes (same lq group) that share these 4 rows
        #pragma unroll
        for (int off = 1; off < 16; off <<= 1) {
            #pragma unroll
            for (int i = 0; i < 4; ++i) {
                const float mo = __shfl_xor(mrow[i], off);
                const float lo = __shfl_xor(lrow[i], off);
                const float d  = mo - mrow[i];
                const float e  = __expf(-fabsf(d));
                lrow[i] = (d <= 0.f) ? fmaf(lo, e, lrow[i]) : fmaf(lrow[i], e, lo);
                mrow[i] = fmaxf(mrow[i], mo);
            }
        }
        if (lm == 0) {
            #pragma unroll
            for (int i = 0; i < 4; ++i) {
                Mw[wv][lq * 4 + i] = mrow[i];
                Lw[wv][lq * 4 + i] = lrow[i];
            }
        }
    }
    __syncthreads();

    // 16 threads per row from here on
    const int r = tid >> 4;     // row 0..15
    const int g = tid & 15;     // chunk index within row

    // ---------- combine the 4 per-wave (m,l) pairs -> row max + 1/sum ----------
    float rmax, rl;
    {
        float M = Mw[0][r], L = Lw[0][r];
        #pragma unroll
        for (int w = 1; w < 4; ++w) {
            const float mo = Mw[w][r], lo = Lw[w][r];
            const float d  = mo - M;
            const float e  = __expf(-fabsf(d));
            L = (d <= 0.f) ? fmaf(lo, e, L) : fmaf(L, e, lo);
            M = fmaxf(M, mo);
        }
        rmax = M;
        rl = 1.0f / L;
    }

    // ---------- Single pass: write attention (float4), store P bf16 in-place ----------
    {
        float* ap = att + ((size_t)bh * S_LEN + q0 + r) * S_LEN;
        for (int k = 0; k < 32; ++k) {
            const int c = g * 4 + k * 64;
            bf16x4 sv = *(const bf16x4*)(&Ss[r][c]);
            float4 p;
            p.x = __expf((float)sv[0] - rmax) * rl;
            p.y = __expf((float)sv[1] - rmax) * rl;
            p.z = __expf((float)sv[2] - rmax) * rl;
            p.w = __expf((float)sv[3] - rmax) * rl;
            *(float4*)(ap + c) = p;
            bf16x4 pb;
            pb[0] = (__bf16)p.x; pb[1] = (__bf16)p.y;
            pb[2] = (__bf16)p.z; pb[3] = (__bf16)p.w;
            *(bf16x4*)(&Ss[r][c]) = pb;
        }
    }
    __syncthreads();

    // ---------- Phase B: O = P V (each wave owns 16 output cols) ----------
    {
        const float* vb = V + (size_t)bh * S_LEN * D_DIM + wv * 16 + lm;
        f32x4 o = {0.f, 0.f, 0.f, 0.f};
        for (int kc = 0; kc < 64; ++kc) {
            bf16x8 af = *(const bf16x8*)(&Ss[lm][kc * 32 + lq * 8]);   // A: P[m=lm][k]
            const float* vp = vb + (size_t)(kc * 32 + lq * 8) * D_DIM; // B: V[k][n=lm]
            bf16x8 bfr;
            #pragma unroll
            for (int j = 0; j < 8; ++j)
                bfr[j] = (__bf16)vp[(size_t)j * D_DIM];
            o = __builtin_amdgcn_mfma_f32_16x16x32_bf16(af, bfr, o, 0, 0, 0);
        }
        float* op = out + ((size_t)bh * S_LEN + q0 + lq * 4) * D_DIM + wv * 16 + lm;
        #pragma unroll
        for (int i = 0; i < 4; ++i)
            op[(size_t)i * D_DIM] = o[i];
    }
}

extern "C" void kernel_launch(void* const* d_in, const int* in_sizes, int n_in,
                              void* d_out, int out_size, void* d_ws, size_t ws_size,
                              hipStream_t stream) {
    const float* Q    = (const float*)d_in[0];
    const float* K    = (const float*)d_in[1];
    const float* V    = (const float*)d_in[2];
    const int*   mask = (const int*)d_in[3];
    const int*   sc   = (const int*)d_in[4];
    float* out = (float*)d_out;
    float* att = out + (size_t)4 * 16 * S_LEN * D_DIM;   // O first, then attention

    dim3 grid(S_LEN / TQ, 4 * 16);   // 128 q-tiles x 64 (b,h)
    sdpa_kernel<<<grid, 256, 0, stream>>>(Q, K, V, mask, sc, out, att);
}